// Round 1
// baseline (99.920 us; speedup 1.0000x reference)
//
#include <hip/hip_runtime.h>

#define BB 8
#define TT 128
#define DD 256

__global__ void zero_out_kernel(float* __restrict__ out) {
    int i = blockIdx.x * blockDim.x + threadIdx.x;
    if (i < BB * DD) out[i] = 0.0f;
}

// One block per (b,t). 256 threads as 16x16 grid; thread (ty,tx) computes the
// 16x16 sub-tile M[p][q], p in [ty*16,ty*16+16), q in [tx*16,tx*16+16),
// M[p][q] = exp(dec[b,p] * enc[b,t,q]); accumulates partial column sums
// (over p, indexed by q) and partial row sums (over q, indexed by p).
// LDS transpose-reduce gives full colsum[q], rowsum[q]; contribution
// enc[b,t,q] * colsum[q]/rowsum[q] is atomically accumulated over t.
__global__ __launch_bounds__(256, 4) void attn_tile_kernel(
    const float* __restrict__ dec,   // [B, D]
    const float* __restrict__ enc,   // [B, T, D]
    float* __restrict__ out) {       // [B, D], pre-zeroed
    __shared__ __align__(16) float sd[DD];
    __shared__ __align__(16) float se[DD];
    __shared__ float scol[16 * 257];  // [chunk ty][q], pitch 257 to spread banks
    __shared__ float srow[16 * 257];  // [chunk tx][p]

    const int blk = blockIdx.x;
    const int b = blk >> 7;          // / TT
    const int t = blk & (TT - 1);
    const int tid = threadIdx.x;
    const int tx = tid & 15;
    const int ty = tid >> 4;

    sd[tid] = dec[b * DD + tid];
    se[tid] = enc[(b * TT + t) * DD + tid];
    __syncthreads();

    // Stage this thread's 16 d-values and 16 e-values into registers (b128 reads).
    float dloc[16], eloc[16];
    #pragma unroll
    for (int k = 0; k < 4; ++k) {
        float4 v = *reinterpret_cast<const float4*>(&sd[ty * 16 + k * 4]);
        dloc[k * 4 + 0] = v.x; dloc[k * 4 + 1] = v.y;
        dloc[k * 4 + 2] = v.z; dloc[k * 4 + 3] = v.w;
        float4 w = *reinterpret_cast<const float4*>(&se[tx * 16 + k * 4]);
        eloc[k * 4 + 0] = w.x; eloc[k * 4 + 1] = w.y;
        eloc[k * 4 + 2] = w.z; eloc[k * 4 + 3] = w.w;
    }

    float cpart[16];
    #pragma unroll
    for (int j = 0; j < 16; ++j) cpart[j] = 0.0f;

    #pragma unroll
    for (int i = 0; i < 16; ++i) {
        const float di = dloc[i];
        float rs = 0.0f;
        #pragma unroll
        for (int j = 0; j < 16; ++j) {
            float m = __expf(di * eloc[j]);   // v_mul + v_exp_f32
            rs += m;
            cpart[j] += m;
        }
        // partial row sum for p = ty*16+i over e-chunk tx
        srow[tx * 257 + ty * 16 + i] = rs;    // banks: 2-way, free
    }
    #pragma unroll
    for (int j = 0; j < 16; ++j) {
        // partial col sum for q = tx*16+j over p-chunk ty
        scol[ty * 257 + tx * 16 + j] = cpart[j];  // banks: <=8-way on 16 insts, cheap
    }
    __syncthreads();

    // Thread tid owns output index q = tid (and row p = tid).
    float cs = 0.0f, rs = 0.0f;
    #pragma unroll
    for (int k = 0; k < 16; ++k) {
        cs += scol[k * 257 + tid];  // conflict-free: consecutive lanes
        rs += srow[k * 257 + tid];
    }

    const float contrib = se[tid] * cs / rs;
    atomicAdd(&out[b * DD + tid], contrib);
}

extern "C" void kernel_launch(void* const* d_in, const int* in_sizes, int n_in,
                              void* d_out, int out_size, void* d_ws, size_t ws_size,
                              hipStream_t stream) {
    const float* dec = (const float*)d_in[0];  // [B, D] fp32
    const float* enc = (const float*)d_in[1];  // [B, T, D] fp32
    float* out = (float*)d_out;                // [B, D] fp32

    zero_out_kernel<<<(BB * DD + 255) / 256, 256, 0, stream>>>(out);
    attn_tile_kernel<<<BB * TT, 256, 0, stream>>>(dec, enc, out);
}